// Round 18
// baseline (548.875 us; speedup 1.0000x reference)
//
#include <hip/hip_runtime.h>
#include <hip/hip_bf16.h>
#include <math.h>

#define B_    8
#define CIN   32
#define CO    64
#define NN    512
#define TT    24
#define NT    (NN*TT)        /* 12288 */
#define LNCNT (CO*NT)        /* 786432 */
#define EPSL  1e-5f
#define MAXNZ 64
#define HSS   28             /* fp32 LDS row stride (hbuild) */

typedef const float* fp;
static __device__ __forceinline__ float lk(float x){ return x > 0.f ? x : 0.01f*x; }
static __device__ __forceinline__ float sg(float x){
    if(x >= 0.f){ float e = expf(-x); return 1.f/(1.f+e); }
    float e = expf(x); return e/(1.f+e);
}
// bf16 pair pack/unpack (lo = even element, hi = odd element)
static __device__ __forceinline__ unsigned pk2(float a, float b){
    __hip_bfloat16 x = __float2bfloat16(a), y = __float2bfloat16(b);
    unsigned lo = *(unsigned short*)&x, hi = *(unsigned short*)&y;
    return lo | (hi<<16);
}
static __device__ __forceinline__ float lo2f(unsigned u){ return __uint_as_float(u<<16); }
static __device__ __forceinline__ float hi2f(unsigned u){ return __uint_as_float(u & 0xffff0000u); }

// ---------------- CSC build from adj (2% dense), fully parallel ----------------
__global__ __launch_bounds__(256) void k_csc(fp adj, int* cnt, int* idx, float* val){
    int e = blockIdx.x*blockDim.x + threadIdx.x;   // 0 .. NN*NN-1
    if(e >= NN*NN) return;
    float a = adj[e];
    if(a != 0.f){
        int u = e >> 9, q = e & 511;
        int slot = atomicAdd(&cnt[q], 1);
        if(slot < MAXNZ){ idx[q*MAXNZ+slot] = u; val[q*MAXNZ+slot] = a; }
    }
}
__global__ void k_deg(int* cnt, float* deginv){
    int q = blockIdx.x*blockDim.x + threadIdx.x;
    if(q < NN){
        int c = cnt[q];
        deginv[q] = 1.f / (c < 1 ? 1.f : (float)c);
        if(c > MAXNZ) cnt[q] = MAXNZ;
    }
}

// ---- conv1 (1x1) + temporal conv (1x3) + LN stats; block=(b, 4-n tile) ----
__global__ __launch_bounds__(256) void k_conv(fp x, fp w1, fp b1, fp wt, fp bt,
        float* xin, float* x1p, float* stats){
    __shared__ float xs[4*858];          // [nl][c*26 + t], nl-stride 858 (%32==26)
    __shared__ float w1s[CO*33];         // stride 33: bank=(o+c)%32, conflict-free
    __shared__ float wtA[CO*33], wtB[CO*33], wtC[CO*33];
    __shared__ float red[256];
    int bid = blockIdx.x; int b = bid>>7; int n0 = (bid&127)*4;
    int tid = threadIdx.x;
    for(int j=tid;j<CIN*4*TT;j+=256){
        int c = j/96; int r = j%96; int nl = r/24; int t = r%24;
        xs[nl*858 + c*26 + t+1] = x[((b*CIN+c)*NN + n0+nl)*TT + t];
    }
    for(int j=tid;j<CIN*4;j+=256){ int c=j>>2; int nl=j&3; xs[nl*858+c*26]=0.f; xs[nl*858+c*26+25]=0.f; }
    for(int j=tid;j<CO*CIN;j+=256){ int o=j>>5,c=j&31; w1s[o*33+c]=w1[j]; }
    for(int j=tid;j<CO*CIN*3;j+=256){ int o=j/96; int r=j%96; int c=r/3; int k=r%3;
        float v=wt[j]; if(k==0) wtA[o*33+c]=v; else if(k==1) wtB[o*33+c]=v; else wtC[o*33+c]=v; }
    __syncthreads();
    int o = tid>>2, nl = tid&3;
    float a0[TT], a1[TT];
    float bb1=b1[o], bbt=bt[o];
    #pragma unroll
    for(int t=0;t<TT;++t){ a0[t]=bb1; a1[t]=bbt; }
    const float* xrow = &xs[nl*858];
    for(int c=0;c<CIN;++c){
        float w1c=w1s[o*33+c], q0=wtA[o*33+c], q1=wtB[o*33+c], q2=wtC[o*33+c];
        float xr[26];
        #pragma unroll
        for(int t=0;t<26;++t) xr[t]=xrow[c*26+t];
        #pragma unroll
        for(int t=0;t<TT;++t){
            a0[t] += xr[t+1]*w1c;
            a1[t] += xr[t]*q0 + xr[t+1]*q1 + xr[t+2]*q2;
        }
    }
    size_t base = (size_t)(b*CO+o)*NT + (size_t)(n0+nl)*TT;
    #pragma unroll
    for(int k=0;k<6;++k){
        *(float4*)(xin + base + 4*k) = make_float4(a0[4*k],a0[4*k+1],a0[4*k+2],a0[4*k+3]);
        *(float4*)(x1p + base + 4*k) = make_float4(a1[4*k],a1[4*k+1],a1[4*k+2],a1[4*k+3]);
    }
    float ls=0.f, lsq=0.f;
    #pragma unroll
    for(int t=0;t<TT;++t){ ls+=a1[t]; lsq+=a1[t]*a1[t]; }
    red[tid]=ls; __syncthreads();
    for(int s=128;s>0;s>>=1){ if(tid<s) red[tid]+=red[tid+s]; __syncthreads(); }
    float tsum = red[0]; __syncthreads();
    red[tid]=lsq; __syncthreads();
    for(int s=128;s>0;s>>=1){ if(tid<s) red[tid]+=red[tid+s]; __syncthreads(); }
    if(tid==0){ atomicAdd(&stats[b], tsum); atomicAdd(&stats[8+b], red[0]); }
}

// ---------------- finalize per-batch LN stats ----------------
__global__ void k_stat(float* stats, int off){
    int b = threadIdx.x;
    if(b < 8){
        float m = stats[off+b] / (float)LNCNT;
        float v = stats[off+8+b] / (float)LNCNT - m*m;
        v = fmaxf(v, 0.f);
        stats[off+16+b] = m;
        stats[off+24+b] = rsqrtf(v + EPSL);
    }
}

// ---- LN+leaky (fused) then h = stack(4*x1, adj^T x1) ----
__global__ __launch_bounds__(256) void k_hbuild(fp x1p, fp lng, fp lnb,
        const float* stats, const int* cnt, const int* idx, const float* val, float* h){
    __shared__ float xs[NN*HSS];          // 57.3 KB
    int blk = blockIdx.x; int b = blk >> 6; int c = blk & 63;
    int tid = threadIdx.x;
    float m = stats[16+b], inv = stats[24+b];
    fp src = x1p + (size_t)(b*CO + c)*NT;
    for(int i=tid;i<NT;i+=256){
        int n = i/TT, t = i%TT;
        xs[n*HSS + t] = lk((src[i] - m)*inv*lng[c*NT + i] + lnb[c*NT + i]);
    }
    __syncthreads();
    float* h0 = h + (size_t)((b*CO+c)*2 + 0)*NT;
    float* h1 = h0 + NT;
    #pragma unroll
    for(int half=0; half<2; ++half){
        int n = tid + half*256;
        float t1[TT], acc[TT];
        const float4* sp = (const float4*)&xs[n*HSS];
        #pragma unroll
        for(int k=0;k<6;++k){
            float4 v = sp[k];
            t1[4*k]=v.x; t1[4*k+1]=v.y; t1[4*k+2]=v.z; t1[4*k+3]=v.w;
        }
        #pragma unroll
        for(int l=0;l<TT;++l) acc[l]=0.f;
        int cq = cnt[n];
        for(int j=0;j<cq;++j){
            int u = idx[n*MAXNZ+j];
            float v = val[n*MAXNZ+j];
            const float4* rp = (const float4*)&xs[u*HSS];
            #pragma unroll
            for(int k=0;k<6;++k){
                float4 w = rp[k];
                acc[4*k]+=v*w.x; acc[4*k+1]+=v*w.y; acc[4*k+2]+=v*w.z; acc[4*k+3]+=v*w.w;
            }
        }
        #pragma unroll
        for(int k=0;k<6;++k){
            *(float4*)(h0 + n*TT + 4*k) =
                make_float4(4.f*t1[4*k],4.f*t1[4*k+1],4.f*t1[4*k+2],4.f*t1[4*k+3]);
            *(float4*)(h1 + n*TT + 4*k) =
                make_float4(acc[4*k],acc[4*k+1],acc[4*k+2],acc[4*k+3]);
        }
    }
}

// ---- fused GraphSAGE x2, bf16 LDS tile, 512 thr/block (1 node/thread) ----
// halves per-thread serial chain, doubles waves/block; live set ~60 floats.
__global__ __launch_bounds__(512) void k_sageF(float* h,
        fp s0ws, fp s0wn, fp s0b, fp s1ws, fp s1wn, fp s1b,
        const int* cnt, const int* idx, const float* deginv){
    __shared__ unsigned hsb[NN*12];       // bf16 pairs, row n at hsb[n*12] (48B)
    __shared__ float wq[TT*48];
    __shared__ float biL[TT];
    int tid = threadIdx.x;
    float* base = h + (size_t)blockIdx.x*NT;
    for(int i=tid;i<NN*12;i+=512){
        float2 v = *(const float2*)(base + 2*i);
        hsb[i] = pk2(v.x, v.y);
    }
    for(int j=tid;j<TT*TT;j+=512){
        int m=j/TT, l=j%TT;
        wq[m*48+2*l]   = s0ws[j];
        wq[m*48+2*l+1] = s0wn[j];
    }
    if(tid<TT) biL[tid]=s0b[tid];
    __syncthreads();
    int n = tid;
    for(int layer=0; layer<2; ++layer){
        float t1[TT], t2[TT];
        {
            const uint4* sp = (const uint4*)&hsb[n*12];
            uint4 A=sp[0], Bv=sp[1], Cv=sp[2];
            t1[0]=lo2f(A.x);  t1[1]=hi2f(A.x);  t1[2]=lo2f(A.y);  t1[3]=hi2f(A.y);
            t1[4]=lo2f(A.z);  t1[5]=hi2f(A.z);  t1[6]=lo2f(A.w);  t1[7]=hi2f(A.w);
            t1[8]=lo2f(Bv.x); t1[9]=hi2f(Bv.x); t1[10]=lo2f(Bv.y);t1[11]=hi2f(Bv.y);
            t1[12]=lo2f(Bv.z);t1[13]=hi2f(Bv.z);t1[14]=lo2f(Bv.w);t1[15]=hi2f(Bv.w);
            t1[16]=lo2f(Cv.x);t1[17]=hi2f(Cv.x);t1[18]=lo2f(Cv.y);t1[19]=hi2f(Cv.y);
            t1[20]=lo2f(Cv.z);t1[21]=hi2f(Cv.z);t1[22]=lo2f(Cv.w);t1[23]=hi2f(Cv.w);
            #pragma unroll
            for(int l=0;l<TT;++l) t2[l]=0.f;
            int cq = cnt[n];
            for(int j=0;j<cq;++j){
                int u = idx[n*MAXNZ+j];
                const uint4* rp = (const uint4*)&hsb[u*12];
                uint4 a=rp[0], bq=rp[1], cq4=rp[2];
                t2[0]+=lo2f(a.x);  t2[1]+=hi2f(a.x);  t2[2]+=lo2f(a.y);  t2[3]+=hi2f(a.y);
                t2[4]+=lo2f(a.z);  t2[5]+=hi2f(a.z);  t2[6]+=lo2f(a.w);  t2[7]+=hi2f(a.w);
                t2[8]+=lo2f(bq.x); t2[9]+=hi2f(bq.x); t2[10]+=lo2f(bq.y);t2[11]+=hi2f(bq.y);
                t2[12]+=lo2f(bq.z);t2[13]+=hi2f(bq.z);t2[14]+=lo2f(bq.w);t2[15]+=hi2f(bq.w);
                t2[16]+=lo2f(cq4.x);t2[17]+=hi2f(cq4.x);t2[18]+=lo2f(cq4.y);t2[19]+=hi2f(cq4.y);
                t2[20]+=lo2f(cq4.z);t2[21]+=hi2f(cq4.z);t2[22]+=lo2f(cq4.w);t2[23]+=hi2f(cq4.w);
            }
            float di = deginv[n];
            #pragma unroll
            for(int l=0;l<TT;++l) t2[l]*=di;
        }
        __syncthreads();   // ALL reads of hsb complete before any write
        for(int mc=0; mc<6; ++mc){
            float oa[4];
            #pragma unroll
            for(int mi=0;mi<4;++mi){
                int m = mc*4+mi;
                float acc = biL[m];
                const float4* wp = (const float4*)&wq[m*48];
                #pragma unroll
                for(int k=0;k<12;++k){
                    float4 w = wp[k];
                    acc += t1[2*k]*w.x + t2[2*k]*w.y + t1[2*k+1]*w.z + t2[2*k+1]*w.w;
                }
                oa[mi]=acc;
            }
            *(uint2*)&hsb[n*12 + mc*2] = make_uint2(pk2(oa[0],oa[1]), pk2(oa[2],oa[3]));
        }
        if(layer==0){
            __syncthreads();   // layer-0 writes visible; wq safe to swap
            for(int j=tid;j<TT*TT;j+=512){
                int m=j/TT, l=j%TT;
                wq[m*48+2*l]   = s1ws[j];
                wq[m*48+2*l+1] = s1wn[j];
            }
            if(tid<TT) biL[tid]=s1b[tid];
            __syncthreads();
        }
    }
    __syncthreads();
    for(int i=tid;i<NN*12;i+=512){
        unsigned u = hsb[i];
        *(float2*)(base + 2*i) = make_float2(lo2f(u), hi2f(u));
    }
}

// ---------------- GLU gating: sigmoid(gate)*leaky(filt) ----------------
__global__ void k_gate(fp h, float* xg){
    int tot = B_*CO*NT/4;
    for(int i = blockIdx.x*blockDim.x + threadIdx.x; i<tot; i += gridDim.x*blockDim.x){
        int f = i*4;
        int b = f / (CO*NT);
        int r = f % (CO*NT);
        const float4 fl = *(const float4*)(h + (size_t)b*2*CO*NT + r);
        const float4 gt = *(const float4*)(h + (size_t)b*2*CO*NT + CO*NT + r);
        float4 o;
        o.x = sg(gt.x) * lk(fl.x);
        o.y = sg(gt.y) * lk(fl.y);
        o.z = sg(gt.z) * lk(fl.z);
        o.w = sg(gt.w) * lk(fl.w);
        *(float4*)(xg + (size_t)b*CO*NT + r) = o;
    }
}

// ---------------- f1[b,l,n] = sum_c xg[b,c,n,l]*w1[c] ----------------
__global__ __launch_bounds__(256) void k_f1(fp xg, fp w1, float* f1){
    int blk = blockIdx.x; int b = blk/16; int n0 = (blk%16)*32;
    int tid = threadIdx.x;
    float acc[3] = {0.f,0.f,0.f};
    for(int c=0;c<CO;++c){
        float w = w1[c];
        fp src = xg + (size_t)(b*CO+c)*NT + n0*TT;
        #pragma unroll
        for(int r=0;r<3;++r) acc[r] += src[tid + 256*r]*w;
    }
    #pragma unroll
    for(int r=0;r<3;++r){
        int p = tid + 256*r;
        int nl = p/TT, t = p%TT;
        f1[(b*TT+t)*NN + n0+nl] = acc[r];
    }
}

// ---------------- f2[b,c,l] = sum_n xg[b,c,n,l]*w2[n] ----------------
__global__ __launch_bounds__(256) void k_f2(fp xg, fp w2, float* f2){
    __shared__ float red[256*TT];
    int blk = blockIdx.x; int b = blk/CO; int c = blk%CO;
    int tid = threadIdx.x;
    float acc[TT];
    #pragma unroll
    for(int l=0;l<TT;++l) acc[l]=0.f;
    fp src = xg + (size_t)(b*CO+c)*NT;
    for(int n=tid;n<NN;n+=256){
        float w = w2[n];
        #pragma unroll
        for(int l=0;l<TT;++l) acc[l] += src[n*TT+l]*w;
    }
    #pragma unroll
    for(int l=0;l<TT;++l) red[tid*TT+l]=acc[l];
    __syncthreads();
    for(int s=128;s>0;s>>=1){
        if(tid<s){
            #pragma unroll
            for(int l=0;l<TT;++l) red[tid*TT+l]+=red[(tid+s)*TT+l];
        }
        __syncthreads();
    }
    if(tid<TT) f2[(b*CO+c)*TT+tid] = red[tid];
}

// ---------------- dilated(2) conv over n on f1 ----------------
__global__ __launch_bounds__(256) void k_conv_f1(fp f1, fp wd1, float* f1c){
    __shared__ float fs[TT][NN+2];
    __shared__ float w0[TT*TT], w1a[TT*TT];
    int b = blockIdx.x; int tid=threadIdx.x;
    for(int i=tid;i<TT*NN;i+=256){ int l=i/NN,n=i%NN; fs[l][n+1]=f1[(b*TT+l)*NN+n]; }
    for(int l=tid;l<TT;l+=256){ fs[l][0]=0.f; fs[l][NN+1]=0.f; }
    for(int i=tid;i<TT*TT;i+=256){ w0[i]=wd1[i*2]; w1a[i]=wd1[i*2+1]; }
    __syncthreads();
    for(int j=tid;j<TT*NN;j+=256){
        int o=j/NN, n=j%NN;
        float acc=0.f;
        #pragma unroll
        for(int i=0;i<TT;++i) acc += fs[i][n]*w0[o*TT+i] + fs[i][n+2]*w1a[o*TT+i];
        f1c[(b*TT+o)*NN+n]=acc;
    }
}

// ---------------- dilated(2) conv over l on f2 ----------------
__global__ __launch_bounds__(256) void k_conv_f2(fp f2, fp wd2, float* f2c){
    __shared__ float fs[CO][TT+2];
    __shared__ float w0[CO*CO], w1a[CO*CO];
    int b = blockIdx.x; int tid=threadIdx.x;
    for(int i=tid;i<CO*TT;i+=256){ int c=i/TT,l=i%TT; fs[c][l+1]=f2[(b*CO+c)*TT+l]; }
    for(int c=tid;c<CO;c+=256){ fs[c][0]=0.f; fs[c][TT+1]=0.f; }
    for(int i=tid;i<CO*CO;i+=256){ w0[i]=wd2[i*2]; w1a[i]=wd2[i*2+1]; }
    __syncthreads();
    for(int j=tid;j<CO*TT;j+=256){
        int o=j/TT, l=j%TT;
        float acc=0.f;
        for(int i=0;i<CO;++i) acc += fs[i][l]*w0[o*CO+i] + fs[i][l+2]*w1a[o*CO+i];
        f2c[(b*CO+o)*TT+l]=acc;
    }
}

// ---------------- g1[b,l,c] = sum_n f1c[b,l,n]*tW[n,c] ----------------
__global__ __launch_bounds__(256) void k_g1(fp f1c, fp tW, float* g1){
    __shared__ float fs[TT*NN];
    int b=blockIdx.x; int tid=threadIdx.x;
    for(int i=tid;i<TT*NN;i+=256) fs[i]=f1c[b*TT*NN+i];
    __syncthreads();
    int c = tid & 63; int lg = tid >> 6;
    float acc[6]={0.f,0.f,0.f,0.f,0.f,0.f};
    for(int n=0;n<NN;++n){
        float w = tW[n*CO + c];
        #pragma unroll
        for(int r=0;r<6;++r) acc[r] += fs[(lg*6+r)*NN + n]*w;
    }
    #pragma unroll
    for(int r=0;r<6;++r) g1[(b*TT + lg*6+r)*CO + c] = acc[r];
}

// ---------------- logits -> sigmoid -> t_v -> BN -> masked softmax -> T_coef ----------------
__global__ __launch_bounds__(256) void k_logits(fp g1, fp f2c,
        fp tbias, fp tv, fp bng, fp bnb, float* coefs, float* tco){
    __shared__ float sig[B_*TT*TT];
    __shared__ float lg2[B_*TT*TT];
    __shared__ float muq[TT], scq[TT], shq[TT];
    int tid=threadIdx.x;
    for(int j=tid;j<B_*TT*TT;j+=256){
        int b=j/(TT*TT); int r=j%(TT*TT); int l=r/TT; int q=r%TT;
        float acc = tbias[l*TT+q];
        fp gg = g1 + (b*TT+l)*CO;
        fp ff = f2c + b*CO*TT + q;
        for(int c=0;c<CO;++c) acc += gg[c]*ff[c*TT];
        sig[j] = sg(acc);
    }
    __syncthreads();
    for(int j=tid;j<B_*TT*TT;j+=256){
        int b=j/(TT*TT); int r=j%(TT*TT); int l=r/TT; int q=r%TT;
        float acc=0.f;
        for(int k=0;k<TT;++k) acc += tv[l*TT+k]*sig[(b*TT+k)*TT+q];
        lg2[j]=acc;
    }
    __syncthreads();
    if(tid<TT){
        int q=tid;
        float s=0.f;
        for(int b=0;b<B_;++b) for(int l=0;l<TT;++l) s += lg2[(b*TT+l)*TT+q];
        float mu = s/192.f;
        float v=0.f;
        for(int b=0;b<B_;++b) for(int l=0;l<TT;++l){ float d = lg2[(b*TT+l)*TT+q]-mu; v += d*d; }
        v = fmaxf(v/192.f, 0.f);
        muq[q]=mu; scq[q]=rsqrtf(v+EPSL)*bng[q]; shq[q]=bnb[q];
    }
    __syncthreads();
    if(tid<192){
        int b=tid/TT, l=tid%TT;
        int base = (l<12)?0:12;
        float z[12];
        float mx=-1e30f;
        #pragma unroll
        for(int r=0;r<12;++r){
            int q=base+r;
            float zv=(lg2[(b*TT+l)*TT+q]-muq[q])*scq[q]+shq[q];
            z[r]=zv; mx = fmaxf(mx,zv);
        }
        float s=0.f;
        #pragma unroll
        for(int r=0;r<12;++r){ z[r]=expf(z[r]-mx); s+=z[r]; }
        float is=1.f/s;
        for(int q=0;q<TT;++q){
            float cf = (q>=base && q<base+12) ? z[q-base]*is : 0.f;
            coefs[(b*TT+l)*TT+q]=cf;
            tco[(b*TT+q)*TT+l]=cf;
        }
    }
}

// ---- x1new = xg @ coefs^T ; y = leaky(x1new)+x_input ; LN stats ----
__global__ __launch_bounds__(256) void k_apply(fp xg, fp xin, fp coefs,
        float* y, float* stats){
    __shared__ float cf[TT*TT];
    __shared__ float red[256];
    int blk=blockIdx.x; int b=blk>>6; int c=blk&63; int tid=threadIdx.x;
    for(int i=tid;i<TT*TT;i+=256) cf[i]=coefs[b*TT*TT+i];
    __syncthreads();
    float ls=0.f,lsq=0.f;
    fp srow = xg + (size_t)(b*CO+c)*NT;
    fp xrow = xin + (size_t)(b*CO+c)*NT;
    float* yrow = y + (size_t)(b*CO+c)*NT;
    for(int n=tid;n<NN;n+=256){
        float row[TT], xi[TT], out[TT];
        #pragma unroll
        for(int k=0;k<6;++k){
            float4 v = *(const float4*)(srow + n*TT + 4*k);
            row[4*k]=v.x; row[4*k+1]=v.y; row[4*k+2]=v.z; row[4*k+3]=v.w;
            float4 u = *(const float4*)(xrow + n*TT + 4*k);
            xi[4*k]=u.x; xi[4*k+1]=u.y; xi[4*k+2]=u.z; xi[4*k+3]=u.w;
        }
        #pragma unroll
        for(int q=0;q<TT;++q){
            float acc=0.f;
            #pragma unroll
            for(int l=0;l<TT;++l) acc+=row[l]*cf[q*TT+l];
            float yv = lk(acc) + xi[q];
            out[q]=yv;
            ls+=yv; lsq+=yv*yv;
        }
        #pragma unroll
        for(int k=0;k<6;++k)
            *(float4*)(yrow + n*TT + 4*k) = make_float4(out[4*k],out[4*k+1],out[4*k+2],out[4*k+3]);
    }
    red[tid]=ls; __syncthreads();
    for(int s=128;s>0;s>>=1){ if(tid<s) red[tid]+=red[tid+s]; __syncthreads(); }
    float t0=red[0]; __syncthreads();
    red[tid]=lsq; __syncthreads();
    for(int s=128;s>0;s>>=1){ if(tid<s) red[tid]+=red[tid+s]; __syncthreads(); }
    if(tid==0){ atomicAdd(&stats[32+b], t0); atomicAdd(&stats[40+b], red[0]); }
}

// ---------------- final LN apply ----------------
__global__ void k_final(fp y, fp lng, fp lnb, const float* stats, float* out){
    int tot = B_*CO*NT;
    for(int i = blockIdx.x*blockDim.x + threadIdx.x; i<tot; i+=gridDim.x*blockDim.x){
        int b = i/LNCNT; int r = i%LNCNT;
        out[i] = (y[i]-stats[48+b])*stats[56+b]*lng[r]+lnb[r];
    }
}

extern "C" void kernel_launch(void* const* d_in, const int* in_sizes, int n_in,
                              void* d_out, int out_size, void* d_ws, size_t ws_size,
                              hipStream_t stream){
    fp x    = (fp)d_in[0];
    fp adj  = (fp)d_in[1];
    fp w1   = (fp)d_in[2];
    fp b1   = (fp)d_in[3];
    fp wt   = (fp)d_in[4];
    fp bt   = (fp)d_in[5];
    fp lng  = (fp)d_in[6];
    fp lnb  = (fp)d_in[7];
    fp s0ws = (fp)d_in[8];
    fp s0wn = (fp)d_in[9];
    fp s0b  = (fp)d_in[10];
    fp s1ws = (fp)d_in[11];
    fp s1wn = (fp)d_in[12];
    fp s1b  = (fp)d_in[13];
    fp tw1  = (fp)d_in[14];
    fp tw2  = (fp)d_in[15];
    fp twd1 = (fp)d_in[16];
    fp twd2 = (fp)d_in[17];
    fp tW   = (fp)d_in[18];
    fp tbias= (fp)d_in[19];
    fp tv   = (fp)d_in[20];
    fp bng  = (fp)d_in[21];
    fp bnb  = (fp)d_in[22];

    float* W = (float*)d_ws;            // stats [0..63]
    int*   CNTp = (int*)(W+256);        // 512 ints (zeroed each launch)
    float* DEG  = W+768;
    int*   IDXp = (int*)(W+1280);
    float* VALp = W+34048;
    float* F1   = W+66816;
    float* F1C  = W+165120;
    float* F2   = W+263424;
    float* F2C  = W+275712;
    float* G1   = W+288000;
    float* CF   = W+300288;
    float* XIN  = W+304896;
    float* X1   = W+6596352;
    float* XG   = W+12887808;
    float* HA   = W+19179264;
    float* Y    = W+31762176;           // ends 38053632 floats = 152.2 MB

    float* oout   = (float*)d_out;
    float* o_adj  = oout + 6291456;
    float* o_tc   = oout + 6291456 + 262144;

    hipMemsetAsync(W, 0, 768*sizeof(float), stream);   // stats + cnt
    k_csc<<<1024,256,0,stream>>>(adj, CNTp, IDXp, VALp);
    k_deg<<<2,256,0,stream>>>(CNTp, DEG);
    k_conv<<<1024,256,0,stream>>>(x, w1, b1, wt, bt, XIN, X1, W);
    k_stat<<<1,64,0,stream>>>(W, 0);
    k_hbuild<<<512,256,0,stream>>>(X1, lng, lnb, W, CNTp, IDXp, VALp, HA);
    k_sageF<<<1024,512,0,stream>>>(HA, s0ws, s0wn, s0b, s1ws, s1wn, s1b, CNTp, IDXp, DEG);
    k_gate<<<2048,256,0,stream>>>(HA, XG);
    k_f1<<<128,256,0,stream>>>(XG, tw1, F1);
    k_f2<<<512,256,0,stream>>>(XG, tw2, F2);
    k_conv_f1<<<8,256,0,stream>>>(F1, twd1, F1C);
    k_conv_f2<<<8,256,0,stream>>>(F2, twd2, F2C);
    k_g1<<<8,256,0,stream>>>(F1C, tW, G1);
    k_logits<<<1,256,0,stream>>>(G1, F2C, tbias, tv, bng, bnb, CF, o_tc);
    hipMemcpyAsync(o_adj, d_in[1], 262144*sizeof(float), hipMemcpyDeviceToDevice, stream);
    k_apply<<<512,256,0,stream>>>(XG, XIN, CF, Y, W);
    k_stat<<<1,64,0,stream>>>(W, 32);
    k_final<<<2048,256,0,stream>>>(Y, lng, lnb, W, oout);
}

// Round 19
// 524.245 us; speedup vs baseline: 1.0470x; 1.0470x over previous
//
#include <hip/hip_runtime.h>
#include <hip/hip_bf16.h>
#include <math.h>

#define B_    8
#define CIN   32
#define CO    64
#define NN    512
#define TT    24
#define NT    (NN*TT)        /* 12288 */
#define LNCNT (CO*NT)        /* 786432 */
#define EPSL  1e-5f
#define MAXNZ 64
#define HSS   28             /* fp32 LDS row stride (hbuild) */

typedef const float* fp;
static __device__ __forceinline__ float lk(float x){ return x > 0.f ? x : 0.01f*x; }
static __device__ __forceinline__ float sg(float x){
    if(x >= 0.f){ float e = expf(-x); return 1.f/(1.f+e); }
    float e = expf(x); return e/(1.f+e);
}
// bf16 pair pack/unpack (lo = even element, hi = odd element)
static __device__ __forceinline__ unsigned pk2(float a, float b){
    __hip_bfloat16 x = __float2bfloat16(a), y = __float2bfloat16(b);
    unsigned lo = *(unsigned short*)&x, hi = *(unsigned short*)&y;
    return lo | (hi<<16);
}
static __device__ __forceinline__ float lo2f(unsigned u){ return __uint_as_float(u<<16); }
static __device__ __forceinline__ float hi2f(unsigned u){ return __uint_as_float(u & 0xffff0000u); }

// ---------------- CSC build from adj (2% dense), fully parallel ----------------
__global__ __launch_bounds__(256) void k_csc(fp adj, int* cnt, int* idx, float* val){
    int e = blockIdx.x*blockDim.x + threadIdx.x;   // 0 .. NN*NN-1
    if(e >= NN*NN) return;
    float a = adj[e];
    if(a != 0.f){
        int u = e >> 9, q = e & 511;
        int slot = atomicAdd(&cnt[q], 1);
        if(slot < MAXNZ){ idx[q*MAXNZ+slot] = u; val[q*MAXNZ+slot] = a; }
    }
}
__global__ void k_deg(int* cnt, float* deginv){
    int q = blockIdx.x*blockDim.x + threadIdx.x;
    if(q < NN){
        int c = cnt[q];
        deginv[q] = 1.f / (c < 1 ? 1.f : (float)c);
        if(c > MAXNZ) cnt[q] = MAXNZ;
    }
}

// ---- conv1 (1x1) + temporal conv (1x3) + LN stats; block=(b, 4-n tile) ----
__global__ __launch_bounds__(256) void k_conv(fp x, fp w1, fp b1, fp wt, fp bt,
        float* xin, float* x1p, float* stats){
    __shared__ float xs[4*858];          // [nl][c*26 + t], nl-stride 858 (%32==26)
    __shared__ float w1s[CO*33];         // stride 33: bank=(o+c)%32, conflict-free
    __shared__ float wtA[CO*33], wtB[CO*33], wtC[CO*33];
    __shared__ float red[256];
    int bid = blockIdx.x; int b = bid>>7; int n0 = (bid&127)*4;
    int tid = threadIdx.x;
    for(int j=tid;j<CIN*4*TT;j+=256){
        int c = j/96; int r = j%96; int nl = r/24; int t = r%24;
        xs[nl*858 + c*26 + t+1] = x[((b*CIN+c)*NN + n0+nl)*TT + t];
    }
    for(int j=tid;j<CIN*4;j+=256){ int c=j>>2; int nl=j&3; xs[nl*858+c*26]=0.f; xs[nl*858+c*26+25]=0.f; }
    for(int j=tid;j<CO*CIN;j+=256){ int o=j>>5,c=j&31; w1s[o*33+c]=w1[j]; }
    for(int j=tid;j<CO*CIN*3;j+=256){ int o=j/96; int r=j%96; int c=r/3; int k=r%3;
        float v=wt[j]; if(k==0) wtA[o*33+c]=v; else if(k==1) wtB[o*33+c]=v; else wtC[o*33+c]=v; }
    __syncthreads();
    int o = tid>>2, nl = tid&3;
    float a0[TT], a1[TT];
    float bb1=b1[o], bbt=bt[o];
    #pragma unroll
    for(int t=0;t<TT;++t){ a0[t]=bb1; a1[t]=bbt; }
    const float* xrow = &xs[nl*858];
    for(int c=0;c<CIN;++c){
        float w1c=w1s[o*33+c], q0=wtA[o*33+c], q1=wtB[o*33+c], q2=wtC[o*33+c];
        float xr[26];
        #pragma unroll
        for(int t=0;t<26;++t) xr[t]=xrow[c*26+t];
        #pragma unroll
        for(int t=0;t<TT;++t){
            a0[t] += xr[t+1]*w1c;
            a1[t] += xr[t]*q0 + xr[t+1]*q1 + xr[t+2]*q2;
        }
    }
    size_t base = (size_t)(b*CO+o)*NT + (size_t)(n0+nl)*TT;
    #pragma unroll
    for(int k=0;k<6;++k){
        *(float4*)(xin + base + 4*k) = make_float4(a0[4*k],a0[4*k+1],a0[4*k+2],a0[4*k+3]);
        *(float4*)(x1p + base + 4*k) = make_float4(a1[4*k],a1[4*k+1],a1[4*k+2],a1[4*k+3]);
    }
    float ls=0.f, lsq=0.f;
    #pragma unroll
    for(int t=0;t<TT;++t){ ls+=a1[t]; lsq+=a1[t]*a1[t]; }
    red[tid]=ls; __syncthreads();
    for(int s=128;s>0;s>>=1){ if(tid<s) red[tid]+=red[tid+s]; __syncthreads(); }
    float tsum = red[0]; __syncthreads();
    red[tid]=lsq; __syncthreads();
    for(int s=128;s>0;s>>=1){ if(tid<s) red[tid]+=red[tid+s]; __syncthreads(); }
    if(tid==0){ atomicAdd(&stats[b], tsum); atomicAdd(&stats[8+b], red[0]); }
}

// ---------------- finalize per-batch LN stats ----------------
__global__ void k_stat(float* stats, int off){
    int b = threadIdx.x;
    if(b < 8){
        float m = stats[off+b] / (float)LNCNT;
        float v = stats[off+8+b] / (float)LNCNT - m*m;
        v = fmaxf(v, 0.f);
        stats[off+16+b] = m;
        stats[off+24+b] = rsqrtf(v + EPSL);
    }
}

// ---- LN+leaky (fused) then h = stack(4*x1, adj^T x1); h stored packed bf16 ----
// pk2 rounding here = identical values sageF previously produced at staging.
__global__ __launch_bounds__(256) void k_hbuild(fp x1p, fp lng, fp lnb,
        const float* stats, const int* cnt, const int* idx, const float* val, unsigned* h){
    __shared__ float xs[NN*HSS];          // 57.3 KB
    int blk = blockIdx.x; int b = blk >> 6; int c = blk & 63;
    int tid = threadIdx.x;
    float m = stats[16+b], inv = stats[24+b];
    fp src = x1p + (size_t)(b*CO + c)*NT;
    for(int i=tid;i<NT;i+=256){
        int n = i/TT, t = i%TT;
        xs[n*HSS + t] = lk((src[i] - m)*inv*lng[c*NT + i] + lnb[c*NT + i]);
    }
    __syncthreads();
    unsigned* h0 = h + (size_t)((b*CO+c)*2 + 0)*(NT/2);
    unsigned* h1 = h0 + NT/2;
    #pragma unroll
    for(int half=0; half<2; ++half){
        int n = tid + half*256;
        float t1[TT], acc[TT];
        const float4* sp = (const float4*)&xs[n*HSS];
        #pragma unroll
        for(int k=0;k<6;++k){
            float4 v = sp[k];
            t1[4*k]=v.x; t1[4*k+1]=v.y; t1[4*k+2]=v.z; t1[4*k+3]=v.w;
        }
        #pragma unroll
        for(int l=0;l<TT;++l) acc[l]=0.f;
        int cq = cnt[n];
        for(int j=0;j<cq;++j){
            int u = idx[n*MAXNZ+j];
            float v = val[n*MAXNZ+j];
            const float4* rp = (const float4*)&xs[u*HSS];
            #pragma unroll
            for(int k=0;k<6;++k){
                float4 w = rp[k];
                acc[4*k]+=v*w.x; acc[4*k+1]+=v*w.y; acc[4*k+2]+=v*w.z; acc[4*k+3]+=v*w.w;
            }
        }
        #pragma unroll
        for(int k=0;k<3;++k){
            *(uint4*)(h0 + n*12 + 4*k) = make_uint4(
                pk2(4.f*t1[8*k],  4.f*t1[8*k+1]), pk2(4.f*t1[8*k+2],4.f*t1[8*k+3]),
                pk2(4.f*t1[8*k+4],4.f*t1[8*k+5]), pk2(4.f*t1[8*k+6],4.f*t1[8*k+7]));
            *(uint4*)(h1 + n*12 + 4*k) = make_uint4(
                pk2(acc[8*k],  acc[8*k+1]), pk2(acc[8*k+2],acc[8*k+3]),
                pk2(acc[8*k+4],acc[8*k+5]), pk2(acc[8*k+6],acc[8*k+7]));
        }
    }
}

// ---- fused GraphSAGE x2, bf16 LDS tile, 512 thr/block; h is packed bf16 ----
// staging/writeback are raw uint copies (no pack math, half the traffic).
__global__ __launch_bounds__(512) void k_sageF(unsigned* h,
        fp s0ws, fp s0wn, fp s0b, fp s1ws, fp s1wn, fp s1b,
        const int* cnt, const int* idx, const float* deginv){
    __shared__ unsigned hsb[NN*12];       // bf16 pairs, row n at hsb[n*12] (48B)
    __shared__ float wq[TT*48];
    __shared__ float biL[TT];
    int tid = threadIdx.x;
    unsigned* base = h + (size_t)blockIdx.x*(NT/2);
    for(int i=tid;i<NN*12;i+=512) hsb[i] = base[i];
    for(int j=tid;j<TT*TT;j+=512){
        int m=j/TT, l=j%TT;
        wq[m*48+2*l]   = s0ws[j];
        wq[m*48+2*l+1] = s0wn[j];
    }
    if(tid<TT) biL[tid]=s0b[tid];
    __syncthreads();
    int n = tid;
    for(int layer=0; layer<2; ++layer){
        float t1[TT], t2[TT];
        {
            const uint4* sp = (const uint4*)&hsb[n*12];
            uint4 A=sp[0], Bv=sp[1], Cv=sp[2];
            t1[0]=lo2f(A.x);  t1[1]=hi2f(A.x);  t1[2]=lo2f(A.y);  t1[3]=hi2f(A.y);
            t1[4]=lo2f(A.z);  t1[5]=hi2f(A.z);  t1[6]=lo2f(A.w);  t1[7]=hi2f(A.w);
            t1[8]=lo2f(Bv.x); t1[9]=hi2f(Bv.x); t1[10]=lo2f(Bv.y);t1[11]=hi2f(Bv.y);
            t1[12]=lo2f(Bv.z);t1[13]=hi2f(Bv.z);t1[14]=lo2f(Bv.w);t1[15]=hi2f(Bv.w);
            t1[16]=lo2f(Cv.x);t1[17]=hi2f(Cv.x);t1[18]=lo2f(Cv.y);t1[19]=hi2f(Cv.y);
            t1[20]=lo2f(Cv.z);t1[21]=hi2f(Cv.z);t1[22]=lo2f(Cv.w);t1[23]=hi2f(Cv.w);
            #pragma unroll
            for(int l=0;l<TT;++l) t2[l]=0.f;
            int cq = cnt[n];
            for(int j=0;j<cq;++j){
                int u = idx[n*MAXNZ+j];
                const uint4* rp = (const uint4*)&hsb[u*12];
                uint4 a=rp[0], bq=rp[1], cq4=rp[2];
                t2[0]+=lo2f(a.x);  t2[1]+=hi2f(a.x);  t2[2]+=lo2f(a.y);  t2[3]+=hi2f(a.y);
                t2[4]+=lo2f(a.z);  t2[5]+=hi2f(a.z);  t2[6]+=lo2f(a.w);  t2[7]+=hi2f(a.w);
                t2[8]+=lo2f(bq.x); t2[9]+=hi2f(bq.x); t2[10]+=lo2f(bq.y);t2[11]+=hi2f(bq.y);
                t2[12]+=lo2f(bq.z);t2[13]+=hi2f(bq.z);t2[14]+=lo2f(bq.w);t2[15]+=hi2f(bq.w);
                t2[16]+=lo2f(cq4.x);t2[17]+=hi2f(cq4.x);t2[18]+=lo2f(cq4.y);t2[19]+=hi2f(cq4.y);
                t2[20]+=lo2f(cq4.z);t2[21]+=hi2f(cq4.z);t2[22]+=lo2f(cq4.w);t2[23]+=hi2f(cq4.w);
            }
            float di = deginv[n];
            #pragma unroll
            for(int l=0;l<TT;++l) t2[l]*=di;
        }
        __syncthreads();   // ALL reads of hsb complete before any write
        for(int mc=0; mc<6; ++mc){
            float oa[4];
            #pragma unroll
            for(int mi=0;mi<4;++mi){
                int m = mc*4+mi;
                float acc = biL[m];
                const float4* wp = (const float4*)&wq[m*48];
                #pragma unroll
                for(int k=0;k<12;++k){
                    float4 w = wp[k];
                    acc += t1[2*k]*w.x + t2[2*k]*w.y + t1[2*k+1]*w.z + t2[2*k+1]*w.w;
                }
                oa[mi]=acc;
            }
            *(uint2*)&hsb[n*12 + mc*2] = make_uint2(pk2(oa[0],oa[1]), pk2(oa[2],oa[3]));
        }
        if(layer==0){
            __syncthreads();   // layer-0 writes visible; wq safe to swap
            for(int j=tid;j<TT*TT;j+=512){
                int m=j/TT, l=j%TT;
                wq[m*48+2*l]   = s1ws[j];
                wq[m*48+2*l+1] = s1wn[j];
            }
            if(tid<TT) biL[tid]=s1b[tid];
            __syncthreads();
        }
    }
    __syncthreads();
    for(int i=tid;i<NN*12;i+=512) base[i] = hsb[i];
}

// ---- GLU gating: sigmoid(gate)*leaky(filt); h packed bf16, xg fp32 ----
__global__ void k_gate(const unsigned* h, float* xg){
    int tot = B_*CO*NT/4;
    for(int i = blockIdx.x*blockDim.x + threadIdx.x; i<tot; i += gridDim.x*blockDim.x){
        int f = i*4;
        int b = f / (CO*NT);
        int r = f % (CO*NT);
        const uint2 fu = *(const uint2*)(h + (size_t)b*CO*NT + (r>>1));
        const uint2 gu = *(const uint2*)(h + (size_t)b*CO*NT + (CO*NT/2) + (r>>1));
        float4 o;
        o.x = sg(lo2f(gu.x)) * lk(lo2f(fu.x));
        o.y = sg(hi2f(gu.x)) * lk(hi2f(fu.x));
        o.z = sg(lo2f(gu.y)) * lk(lo2f(fu.y));
        o.w = sg(hi2f(gu.y)) * lk(hi2f(fu.y));
        *(float4*)(xg + (size_t)b*CO*NT + r) = o;
    }
}

// ---------------- f1[b,l,n] = sum_c xg[b,c,n,l]*w1[c] ----------------
__global__ __launch_bounds__(256) void k_f1(fp xg, fp w1, float* f1){
    int blk = blockIdx.x; int b = blk/16; int n0 = (blk%16)*32;
    int tid = threadIdx.x;
    float acc[3] = {0.f,0.f,0.f};
    for(int c=0;c<CO;++c){
        float w = w1[c];
        fp src = xg + (size_t)(b*CO+c)*NT + n0*TT;
        #pragma unroll
        for(int r=0;r<3;++r) acc[r] += src[tid + 256*r]*w;
    }
    #pragma unroll
    for(int r=0;r<3;++r){
        int p = tid + 256*r;
        int nl = p/TT, t = p%TT;
        f1[(b*TT+t)*NN + n0+nl] = acc[r];
    }
}

// ---------------- f2[b,c,l] = sum_n xg[b,c,n,l]*w2[n] ----------------
__global__ __launch_bounds__(256) void k_f2(fp xg, fp w2, float* f2){
    __shared__ float red[256*TT];
    int blk = blockIdx.x; int b = blk/CO; int c = blk%CO;
    int tid = threadIdx.x;
    float acc[TT];
    #pragma unroll
    for(int l=0;l<TT;++l) acc[l]=0.f;
    fp src = xg + (size_t)(b*CO+c)*NT;
    for(int n=tid;n<NN;n+=256){
        float w = w2[n];
        #pragma unroll
        for(int l=0;l<TT;++l) acc[l] += src[n*TT+l]*w;
    }
    #pragma unroll
    for(int l=0;l<TT;++l) red[tid*TT+l]=acc[l];
    __syncthreads();
    for(int s=128;s>0;s>>=1){
        if(tid<s){
            #pragma unroll
            for(int l=0;l<TT;++l) red[tid*TT+l]+=red[(tid+s)*TT+l];
        }
        __syncthreads();
    }
    if(tid<TT) f2[(b*CO+c)*TT+tid] = red[tid];
}

// ---------------- dilated(2) conv over n on f1 ----------------
__global__ __launch_bounds__(256) void k_conv_f1(fp f1, fp wd1, float* f1c){
    __shared__ float fs[TT][NN+2];
    __shared__ float w0[TT*TT], w1a[TT*TT];
    int b = blockIdx.x; int tid=threadIdx.x;
    for(int i=tid;i<TT*NN;i+=256){ int l=i/NN,n=i%NN; fs[l][n+1]=f1[(b*TT+l)*NN+n]; }
    for(int l=tid;l<TT;l+=256){ fs[l][0]=0.f; fs[l][NN+1]=0.f; }
    for(int i=tid;i<TT*TT;i+=256){ w0[i]=wd1[i*2]; w1a[i]=wd1[i*2+1]; }
    __syncthreads();
    for(int j=tid;j<TT*NN;j+=256){
        int o=j/NN, n=j%NN;
        float acc=0.f;
        #pragma unroll
        for(int i=0;i<TT;++i) acc += fs[i][n]*w0[o*TT+i] + fs[i][n+2]*w1a[o*TT+i];
        f1c[(b*TT+o)*NN+n]=acc;
    }
}

// ---------------- dilated(2) conv over l on f2 ----------------
__global__ __launch_bounds__(256) void k_conv_f2(fp f2, fp wd2, float* f2c){
    __shared__ float fs[CO][TT+2];
    __shared__ float w0[CO*CO], w1a[CO*CO];
    int b = blockIdx.x; int tid=threadIdx.x;
    for(int i=tid;i<CO*TT;i+=256){ int c=i/TT,l=i%TT; fs[c][l+1]=f2[(b*CO+c)*TT+l]; }
    for(int c=tid;c<CO;c+=256){ fs[c][0]=0.f; fs[c][TT+1]=0.f; }
    for(int i=tid;i<CO*CO;i+=256){ w0[i]=wd2[i*2]; w1a[i]=wd2[i*2+1]; }
    __syncthreads();
    for(int j=tid;j<CO*TT;j+=256){
        int o=j/TT, l=j%TT;
        float acc=0.f;
        for(int i=0;i<CO;++i) acc += fs[i][l]*w0[o*CO+i] + fs[i][l+2]*w1a[o*CO+i];
        f2c[(b*CO+o)*TT+l]=acc;
    }
}

// ---------------- g1[b,l,c] = sum_n f1c[b,l,n]*tW[n,c] ----------------
__global__ __launch_bounds__(256) void k_g1(fp f1c, fp tW, float* g1){
    __shared__ float fs[TT*NN];
    int b=blockIdx.x; int tid=threadIdx.x;
    for(int i=tid;i<TT*NN;i+=256) fs[i]=f1c[b*TT*NN+i];
    __syncthreads();
    int c = tid & 63; int lg = tid >> 6;
    float acc[6]={0.f,0.f,0.f,0.f,0.f,0.f};
    for(int n=0;n<NN;++n){
        float w = tW[n*CO + c];
        #pragma unroll
        for(int r=0;r<6;++r) acc[r] += fs[(lg*6+r)*NN + n]*w;
    }
    #pragma unroll
    for(int r=0;r<6;++r) g1[(b*TT + lg*6+r)*CO + c] = acc[r];
}

// ---------------- logits -> sigmoid -> t_v -> BN -> masked softmax -> T_coef ----------------
__global__ __launch_bounds__(256) void k_logits(fp g1, fp f2c,
        fp tbias, fp tv, fp bng, fp bnb, float* coefs, float* tco){
    __shared__ float sig[B_*TT*TT];
    __shared__ float lg2[B_*TT*TT];
    __shared__ float muq[TT], scq[TT], shq[TT];
    int tid=threadIdx.x;
    for(int j=tid;j<B_*TT*TT;j+=256){
        int b=j/(TT*TT); int r=j%(TT*TT); int l=r/TT; int q=r%TT;
        float acc = tbias[l*TT+q];
        fp gg = g1 + (b*TT+l)*CO;
        fp ff = f2c + b*CO*TT + q;
        for(int c=0;c<CO;++c) acc += gg[c]*ff[c*TT];
        sig[j] = sg(acc);
    }
    __syncthreads();
    for(int j=tid;j<B_*TT*TT;j+=256){
        int b=j/(TT*TT); int r=j%(TT*TT); int l=r/TT; int q=r%TT;
        float acc=0.f;
        for(int k=0;k<TT;++k) acc += tv[l*TT+k]*sig[(b*TT+k)*TT+q];
        lg2[j]=acc;
    }
    __syncthreads();
    if(tid<TT){
        int q=tid;
        float s=0.f;
        for(int b=0;b<B_;++b) for(int l=0;l<TT;++l) s += lg2[(b*TT+l)*TT+q];
        float mu = s/192.f;
        float v=0.f;
        for(int b=0;b<B_;++b) for(int l=0;l<TT;++l){ float d = lg2[(b*TT+l)*TT+q]-mu; v += d*d; }
        v = fmaxf(v/192.f, 0.f);
        muq[q]=mu; scq[q]=rsqrtf(v+EPSL)*bng[q]; shq[q]=bnb[q];
    }
    __syncthreads();
    if(tid<192){
        int b=tid/TT, l=tid%TT;
        int base = (l<12)?0:12;
        float z[12];
        float mx=-1e30f;
        #pragma unroll
        for(int r=0;r<12;++r){
            int q=base+r;
            float zv=(lg2[(b*TT+l)*TT+q]-muq[q])*scq[q]+shq[q];
            z[r]=zv; mx = fmaxf(mx,zv);
        }
        float s=0.f;
        #pragma unroll
        for(int r=0;r<12;++r){ z[r]=expf(z[r]-mx); s+=z[r]; }
        float is=1.f/s;
        for(int q=0;q<TT;++q){
            float cf = (q>=base && q<base+12) ? z[q-base]*is : 0.f;
            coefs[(b*TT+l)*TT+q]=cf;
            tco[(b*TT+q)*TT+l]=cf;
        }
    }
}

// ---- x1new = xg @ coefs^T ; y = leaky(x1new)+x_input ; LN stats ----
__global__ __launch_bounds__(256) void k_apply(fp xg, fp xin, fp coefs,
        float* y, float* stats){
    __shared__ float cf[TT*TT];
    __shared__ float red[256];
    int blk=blockIdx.x; int b=blk>>6; int c=blk&63; int tid=threadIdx.x;
    for(int i=tid;i<TT*TT;i+=256) cf[i]=coefs[b*TT*TT+i];
    __syncthreads();
    float ls=0.f,lsq=0.f;
    fp srow = xg + (size_t)(b*CO+c)*NT;
    fp xrow = xin + (size_t)(b*CO+c)*NT;
    float* yrow = y + (size_t)(b*CO+c)*NT;
    for(int n=tid;n<NN;n+=256){
        float row[TT], xi[TT], out[TT];
        #pragma unroll
        for(int k=0;k<6;++k){
            float4 v = *(const float4*)(srow + n*TT + 4*k);
            row[4*k]=v.x; row[4*k+1]=v.y; row[4*k+2]=v.z; row[4*k+3]=v.w;
            float4 u = *(const float4*)(xrow + n*TT + 4*k);
            xi[4*k]=u.x; xi[4*k+1]=u.y; xi[4*k+2]=u.z; xi[4*k+3]=u.w;
        }
        #pragma unroll
        for(int q=0;q<TT;++q){
            float acc=0.f;
            #pragma unroll
            for(int l=0;l<TT;++l) acc+=row[l]*cf[q*TT+l];
            float yv = lk(acc) + xi[q];
            out[q]=yv;
            ls+=yv; lsq+=yv*yv;
        }
        #pragma unroll
        for(int k=0;k<6;++k)
            *(float4*)(yrow + n*TT + 4*k) = make_float4(out[4*k],out[4*k+1],out[4*k+2],out[4*k+3]);
    }
    red[tid]=ls; __syncthreads();
    for(int s=128;s>0;s>>=1){ if(tid<s) red[tid]+=red[tid+s]; __syncthreads(); }
    float t0=red[0]; __syncthreads();
    red[tid]=lsq; __syncthreads();
    for(int s=128;s>0;s>>=1){ if(tid<s) red[tid]+=red[tid+s]; __syncthreads(); }
    if(tid==0){ atomicAdd(&stats[32+b], t0); atomicAdd(&stats[40+b], red[0]); }
}

// ---------------- final LN apply ----------------
__global__ void k_final(fp y, fp lng, fp lnb, const float* stats, float* out){
    int tot = B_*CO*NT;
    for(int i = blockIdx.x*blockDim.x + threadIdx.x; i<tot; i+=gridDim.x*blockDim.x){
        int b = i/LNCNT; int r = i%LNCNT;
        out[i] = (y[i]-stats[48+b])*stats[56+b]*lng[r]+lnb[r];
    }
}

extern "C" void kernel_launch(void* const* d_in, const int* in_sizes, int n_in,
                              void* d_out, int out_size, void* d_ws, size_t ws_size,
                              hipStream_t stream){
    fp x    = (fp)d_in[0];
    fp adj  = (fp)d_in[1];
    fp w1   = (fp)d_in[2];
    fp b1   = (fp)d_in[3];
    fp wt   = (fp)d_in[4];
    fp bt   = (fp)d_in[5];
    fp lng  = (fp)d_in[6];
    fp lnb  = (fp)d_in[7];
    fp s0ws = (fp)d_in[8];
    fp s0wn = (fp)d_in[9];
    fp s0b  = (fp)d_in[10];
    fp s1ws = (fp)d_in[11];
    fp s1wn = (fp)d_in[12];
    fp s1b  = (fp)d_in[13];
    fp tw1  = (fp)d_in[14];
    fp tw2  = (fp)d_in[15];
    fp twd1 = (fp)d_in[16];
    fp twd2 = (fp)d_in[17];
    fp tW   = (fp)d_in[18];
    fp tbias= (fp)d_in[19];
    fp tv   = (fp)d_in[20];
    fp bng  = (fp)d_in[21];
    fp bnb  = (fp)d_in[22];

    float* W = (float*)d_ws;            // stats [0..63]
    int*   CNTp = (int*)(W+256);        // 512 ints (zeroed each launch)
    float* DEG  = W+768;
    int*   IDXp = (int*)(W+1280);
    float* VALp = W+34048;
    float* F1   = W+66816;
    float* F1C  = W+165120;
    float* F2   = W+263424;
    float* F2C  = W+275712;
    float* G1   = W+288000;
    float* CF   = W+300288;
    float* XIN  = W+304896;
    float* X1   = W+6596352;
    float* XG   = W+12887808;
    unsigned* HA = (unsigned*)(W+19179264);   // packed bf16 h: 6291456 uints
    float* Y    = W+31762176;           // ends 38053632 floats = 152.2 MB

    float* oout   = (float*)d_out;
    float* o_adj  = oout + 6291456;
    float* o_tc   = oout + 6291456 + 262144;

    hipMemsetAsync(W, 0, 768*sizeof(float), stream);   // stats + cnt
    k_csc<<<1024,256,0,stream>>>(adj, CNTp, IDXp, VALp);
    k_deg<<<2,256,0,stream>>>(CNTp, DEG);
    k_conv<<<1024,256,0,stream>>>(x, w1, b1, wt, bt, XIN, X1, W);
    k_stat<<<1,64,0,stream>>>(W, 0);
    k_hbuild<<<512,256,0,stream>>>(X1, lng, lnb, W, CNTp, IDXp, VALp, HA);
    k_sageF<<<1024,512,0,stream>>>(HA, s0ws, s0wn, s0b, s1ws, s1wn, s1b, CNTp, IDXp, DEG);
    k_gate<<<2048,256,0,stream>>>(HA, XG);
    k_f1<<<128,256,0,stream>>>(XG, tw1, F1);
    k_f2<<<512,256,0,stream>>>(XG, tw2, F2);
    k_conv_f1<<<8,256,0,stream>>>(F1, twd1, F1C);
    k_conv_f2<<<8,256,0,stream>>>(F2, twd2, F2C);
    k_g1<<<8,256,0,stream>>>(F1C, tW, G1);
    k_logits<<<1,256,0,stream>>>(G1, F2C, tbias, tv, bng, bnb, CF, o_tc);
    hipMemcpyAsync(o_adj, d_in[1], 262144*sizeof(float), hipMemcpyDeviceToDevice, stream);
    k_apply<<<512,256,0,stream>>>(XG, XIN, CF, Y, W);
    k_stat<<<1,64,0,stream>>>(W, 32);
    k_final<<<2048,256,0,stream>>>(Y, lng, lnb, W, oout);
}